// Round 9
// baseline (425.616 us; speedup 1.0000x reference)
//
#include <hip/hip_runtime.h>

#define GH 135
#define GW 240
#define HH 1080
#define WW 1920
#define HWPX (HH*WW)
#define NP 12
#define IT 2               // anchor block-rows per WG (i-strip)
#define JT 12              // anchor blocks (j) per WG
#define NQG 4              // anchor TRIPLES per it-row (3 blocks/thread)
#define NIG 68             // ceil(GH/IT)
#define NJG 20             // GW/JT
#define TROWS (IT+8)       // 10 staged target block-rows
#define TBLK (JT+8)        // 20 staged target blocks per dy-row
#define DSTR (TBLK*64+4)   // 1284 dw: 16B-aligned; dr*1284 %32 = 4*dr (quad shift/row)
#define UNITS_ROW (TBLK*16)// 320 16B-units per dy-row
#define UNITS_TOT (TROWS*UNITS_ROW) // 3200
#define NTHR 256
#define NACT 144           // 9 dy * (2 it * 4 qg * 2 yh)
#define TT_DW (TROWS*DSTR) // 12840 dw = 51360 B -> 3 WG/CU (PROVEN residency, r5)
#define NWG (NIG*NJG)      // 1360 = 8*170 (XCD-exact)

// r8 lesson: 512-thread WGs got only 1 WG/CU resident (cause unresolved) —
// stay in the r5-proven envelope: 256 thr, 51.4KB LDS, 3 WG/CU, 12 waves.
// r9 lever: LDS-read pipe was ~70% busy (dominant). 3-anchor windows raise
// MACs per ds_read_b128 from 7.2 to 9.8 -> read traffic x0.69.
// Swizzled storage (bijective involution, proven r5):
//   stored(blk, y, xh) = blk*64 + ((y*8+xh) ^ 4*kb ^ 16*(y>>2)), kb=(blk>>1)&7
// Write side LINEAR (zero write conflicts); global src inverse-swizzled.

// 8-px fp32 chain + f64 accumulate (argmin-exact vs np reference, proven r1-r8)
#define CHAIN(AV0, AV1, T0, T1, ACC) do { \
    float _d = (AV0).x - (T0).x; float _s = _d*_d; \
    _d = (AV0).y - (T0).y; _s = fmaf(_d,_d,_s); \
    _d = (AV0).z - (T0).z; _s = fmaf(_d,_d,_s); \
    _d = (AV0).w - (T0).w; _s = fmaf(_d,_d,_s); \
    _d = (AV1).x - (T1).x; _s = fmaf(_d,_d,_s); \
    _d = (AV1).y - (T1).y; _s = fmaf(_d,_d,_s); \
    _d = (AV1).z - (T1).z; _s = fmaf(_d,_d,_s); \
    _d = (AV1).w - (T1).w; _s = fmaf(_d,_d,_s); \
    (ACC) += (double)_s; } while(0)

__global__ void __launch_bounds__(NTHR, 2)
hbma_cost_kernel(const float* __restrict__ A, const float* __restrict__ T,
                 int* __restrict__ bestidx) {
    extern __shared__ float lds[];
    float* Tt = lds;

    // XCD swizzle: 1360 WGs = 8 XCDs x 170
    const int lin = blockIdx.x;
    const int g   = (lin & 7) * (NWG / 8) + (lin >> 3);
    const int ig  = g % NIG, jg = g / NIG;
    const int i0  = ig * IT;
    const int j0  = jg * JT;

    const int tid = threadIdx.x;
    const int dy  = tid >> 4;          // 0..8 for active threads
    const int rem = tid & 15;
    const int it  = rem >> 3;          // 0..1
    const int r2  = rem & 7;
    const int qg  = r2 >> 1;           // 0..3 (anchor triple)
    const int yh  = r2 & 1;            // y-half
    const bool act = (tid < NACT);
    const int i   = i0 + it;           // may be >= GH on last strip (guarded)
    const int gi  = i + dy - 4;
    const bool dyValid = act && (i < GH) && (gi >= 0) && (gi < GH);
    const int dr  = it + dy;           // staged row index 0..9
    const int jb0 = j0 + 3 * qg;       // first anchor block of this thread

    // per-p read-offset XOR table (window base 3*qg may be odd -> per-p kb).
    // indexed only by unrolled p -> stays in registers.
    int xq2[11];
#pragma unroll
    for (int p = 0; p < 11; ++p) {
        const int kb = ((3 * qg + p) >> 1) & 7;
        xq2[p] = kb * 4 ^ (yh << 4);
    }

    double acc[3][9];
#pragma unroll
    for (int a = 0; a < 3; ++a)
#pragma unroll
        for (int d = 0; d < 9; ++d) acc[a][d] = 0.0;

    const int gy0 = (i0 - 4) * 8;
    const int gx0 = (j0 - 4) * 8;

    for (int q = 0; q < NP; ++q) {
        const float* Tq = T + (size_t)q * HWPX;
        const float* Aq = A + (size_t)q * HWPX;
        __syncthreads();               // prev compute done before LDS overwrite
        // ---- stage target halo: LINEAR LDS writes, inverse-swizzled global src ----
        for (int w = tid; w < UNITS_TOT; w += NTHR) {
            const int dyr = w / UNITS_ROW;
            const int u   = w - dyr * UNITS_ROW;    // 16B unit within dy-row
            const int blk = u >> 4, v = u & 15;
            const int kb  = (blk >> 1) & 7;
            const int yh2 = v >> 3;
            const int m3  = (v & 7) ^ kb ^ (yh2 << 2);
            const int y   = (yh2 << 2) + (m3 >> 1);
            const int xh4 = m3 & 1;
            const int gy  = gy0 + dyr * 8 + y;
            const int gx  = gx0 + blk * 8 + xh4 * 4;
            if ((unsigned)gy < (unsigned)HH && (unsigned)gx < (unsigned)WW) {
                *(float4*)(Tt + dyr * DSTR + u * 4) =
                    *(const float4*)(Tq + (size_t)gy * WW + gx);
            }
        }
        __syncthreads();
        // ---- SSD: sliding 11-block window serves 3 anchors x 9 dx ----
        if (dyValid) {
            const float* tb = Tt + dr * DSTR + 3 * qg * 64 + yh * 32;
#pragma unroll
            for (int yi = 0; yi < 4; ++yi) {
                // anchor rows for this yi -> 6 f4 regs (L1-hot, 9x dy-redundant)
                float4 aw[3][2];
#pragma unroll
                for (int a = 0; a < 3; ++a) {
                    const float* row = Aq + (size_t)(jb0 + a) * 8
                                     + (size_t)(i * 8 + yh * 4 + yi) * WW;
                    aw[a][0] = *(const float4*)(row);
                    aw[a][1] = *(const float4*)(row + 4);
                }
                // p-chunks of 4/4/3: bounded tw pressure, deep ds ILP
#pragma unroll
                for (int ph = 0; ph < 3; ++ph) {
                    const int pc = (ph < 2) ? 4 : 3;
                    float4 tw0[4], tw1[4];
#pragma unroll
                    for (int pp = 0; pp < 4; ++pp) {
                        if (pp < pc) {
                            const int p  = ph * 4 + pp;
                            const int o0 = (yi * 8) ^ xq2[p];
                            tw0[pp] = *(const float4*)(tb + p * 64 + o0);
                            tw1[pp] = *(const float4*)(tb + p * 64 + (o0 ^ 4));
                        }
                    }
#pragma unroll
                    for (int pp = 0; pp < 4; ++pp) {
                        if (pp < pc) {
                            const int p = ph * 4 + pp;
#pragma unroll
                            for (int a = 0; a < 3; ++a) {
                                const int dxi = p - a;
                                if (dxi >= 0 && dxi < 9)
                                    CHAIN(aw[a][0], aw[a][1], tw0[pp], tw1[pp], acc[a][dxi]);
                            }
                        }
                    }
                }
            }
        }
    }
    // ---- y-half merge via LDS (aliases Tt, barrier-protected) ----
    __syncthreads();
    double* yred = (double*)lds;                     // 72 groups * 27 f64 = 3888 dw
    const int grpId = (it * NQG + qg) * 9 + dy;      // 0..71
    if (act && yh == 1) {
        double* d = yred + grpId * 27;
#pragma unroll
        for (int a = 0; a < 3; ++a)
#pragma unroll
            for (int k = 0; k < 9; ++k) d[a * 9 + k] = acc[a][k];
    }
    __syncthreads();
    double* redc = (double*)(lds + 8192);            // 216 f64 = 432 dw
    int*    redk = (int*)(lds + 8192 + 432);         // 216 int
    if (act && yh == 0) {
        const double* d = yred + grpId * 27;
#pragma unroll
        for (int a = 0; a < 3; ++a)
#pragma unroll
            for (int k = 0; k < 9; ++k) acc[a][k] += d[a * 9 + k];
        // stage-1 argmin over dx (ascending, strict < -> first-k ties)
#pragma unroll
        for (int a = 0; a < 3; ++a) {
            double bc = 1e300; int bk = -1;
            const int jb = jb0 + a;
#pragma unroll
            for (int dxi = 0; dxi < 9; ++dxi) {
                const int gj = jb + dxi - 4;
                if (dyValid && gj >= 0 && gj < GW && acc[a][dxi] < bc) {
                    bc = acc[a][dxi]; bk = dy * 9 + dxi;
                }
            }
            redc[(it * 9 + dy) * JT + 3 * qg + a] = bc;
            redk[(it * 9 + dy) * JT + 3 * qg + a] = bk;
        }
    }
    __syncthreads();
    // ---- stage-2 argmin over dy (ascending, strict <) ----
    if (tid < IT * JT) {
        const int it2 = tid / JT, jt = tid % JT;
        if (i0 + it2 < GH) {
            double c = 1e300; int k = -1;
#pragma unroll
            for (int dyi = 0; dyi < 9; ++dyi) {
                const double v = redc[(it2 * 9 + dyi) * JT + jt];
                if (v < c) { c = v; k = redk[(it2 * 9 + dyi) * JT + jt]; }
            }
            const int dyi = k / 9, dxi = k % 9;
            const int bi = i0 + it2 + dyi - 4;
            const int bj = j0 + jt + dxi - 4;
            bestidx[(i0 + it2) * GW + j0 + jt] = (bi << 8) | bj;
        }
    }
}

__global__ void __launch_bounds__(256) hbma_gather_kernel(const float* __restrict__ A,
                                                          const int* __restrict__ bestidx,
                                                          float* __restrict__ out) {
    const int tid = blockIdx.x * 256 + threadIdx.x;
    const int q   = tid / (HWPX / 4);
    const int rem = tid % (HWPX / 4);
    const int py  = rem / (WW / 4);
    const int c4  = rem % (WW / 4);
    const int i = py >> 3, y = py & 7;
    const int j = c4 >> 1, xh = (c4 & 1) * 4;
    const int idx = bestidx[i * GW + j];
    const int bi = idx >> 8, bj = idx & 255;
    const float4 v = *(const float4*)(A + (size_t)q * HWPX + (size_t)(bi * 8 + y) * WW + bj * 8 + xh);
    *(float4*)(out + (size_t)q * HWPX + (size_t)py * WW + c4 * 4) = v;
}

extern "C" void kernel_launch(void* const* d_in, const int* in_sizes, int n_in,
                              void* d_out, int out_size, void* d_ws, size_t ws_size,
                              hipStream_t stream) {
    const float* A = (const float*)d_in[0];
    const float* T = (const float*)d_in[1];
    float* out = (float*)d_out;
    int* bestidx = (int*)d_ws;

    hipFuncSetAttribute((const void*)hbma_cost_kernel,
                        hipFuncAttributeMaxDynamicSharedMemorySize, TT_DW * 4);

    hipLaunchKernelGGL(hbma_cost_kernel, dim3(NWG), dim3(NTHR), TT_DW * 4, stream,
                       A, T, bestidx);

    const int total4 = (NP * HWPX) / 4;
    hipLaunchKernelGGL(hbma_gather_kernel, dim3(total4 / 256), dim3(256), 0, stream,
                       A, bestidx, out);
}